// Round 6
// baseline (275.511 us; speedup 1.0000x reference)
//
#include <hip/hip_runtime.h>
#include <hip/hip_bf16.h>

#define BB 8
#define SS 2048
#define NN 1024
#define MT (BB*SS)   // 16384
#define NPC 32       // partial chunks per row (8 kc-tiles * 4 wave-columns)
#define NT 16        // K tiles of 64

typedef __attribute__((ext_vector_type(8))) short bf16x8;
typedef __attribute__((ext_vector_type(4))) float f32x4;
typedef unsigned short u16;
typedef unsigned int u32;

__device__ __forceinline__ u16 f2bf(float f) {
  u32 u = __float_as_uint(f);
  u += 0x7fff + ((u >> 16) & 1);
  return (u16)(u >> 16);
}
__device__ __forceinline__ float bf2f(u16 h) {
  return __uint_as_float(((u32)h) << 16);
}

typedef __attribute__((address_space(1))) void GV;
typedef __attribute__((address_space(3))) void LV;
__device__ __forceinline__ void cp16(const void* g, void* l) {
  __builtin_amdgcn_global_load_lds((GV*)g, (LV*)l, 16, 0, 0);
}

#define WAIT6 asm volatile("s_waitcnt vmcnt(6)" ::: "memory")
#define WAIT0 asm volatile("s_waitcnt vmcnt(0)" ::: "memory")
#define LGKM8 asm volatile("s_waitcnt lgkmcnt(8)" ::: "memory")
#define LGKM0 asm volatile("s_waitcnt lgkmcnt(0)" ::: "memory")
#define BARX  __builtin_amdgcn_s_barrier()
#define SCB0  __builtin_amdgcn_sched_barrier(0)

// ------- prep: cast outer -> bf16, rowsum -> r, kb init = mask (1 wave/row) --
__global__ __launch_bounds__(256) void prep_x_kernel(const float* __restrict__ outer,
                                                     const float* __restrict__ mask,
                                                     u16* __restrict__ Xb,
                                                     float* __restrict__ r,
                                                     float* __restrict__ kb) {
  int w = threadIdx.x >> 6, lane = threadIdx.x & 63;
  int row = blockIdx.x * 4 + w;
  const float4* src = (const float4*)(outer + (size_t)row * NN);
  ushort4* dst = (ushort4*)(Xb + (size_t)row * NN);
  float s = 0.f;
#pragma unroll
  for (int u = 0; u < 4; u++) {
    int idx = lane + u * 64;
    float4 v = src[idx];
    ushort4 o;
    o.x = f2bf(v.x); o.y = f2bf(v.y); o.z = f2bf(v.z); o.w = f2bf(v.w);
    dst[idx] = o;
    s += (v.x + v.y) + (v.z + v.w);
  }
#pragma unroll
  for (int off = 1; off < 64; off <<= 1) s += __shfl_xor(s, off);
  if (lane == 0) { r[row] = s; kb[row] = mask[row]; }
}

// ---------------- prep: cast weights -> bf16 (rows 0..1023 = Wq, 1024.. = Wk) --
__global__ __launch_bounds__(256) void prep_w_kernel(const float* __restrict__ Wq,
                                                     const float* __restrict__ Wk,
                                                     const float* __restrict__ bq,
                                                     const float* __restrict__ bk,
                                                     u16* __restrict__ Wb,
                                                     float* __restrict__ bb) {
  int idx = blockIdx.x * 256 + threadIdx.x;   // 0 .. 524287 (x4 elems)
  int e = idx * 4;
  int rowm = e >> 10;
  int col = e & 1023;
  const float* srcp = (rowm < NN) ? (Wq + (size_t)rowm * NN + col)
                                  : (Wk + (size_t)(rowm - NN) * NN + col);
  float4 v = *(const float4*)srcp;
  ushort4 o; o.x = f2bf(v.x); o.y = f2bf(v.y); o.z = f2bf(v.z); o.w = f2bf(v.w);
  *(ushort4*)(Wb + (size_t)e) = o;
  if (idx < 2 * NN) bb[idx] = (idx < NN) ? bq[idx] : bk[idx - NN];
}

// == 256x256 / BK=64 / m201-cadence: 4 phases/tile, 2 barriers/phase,
//    reads+stage BEFORE first barrier, ONE vmcnt(6) per tile at ph4 ==
// LDS per buf (64KB): A half0(16KB) A half1(16KB) Bq0..Bq3(8KB each). 2 bufs.
// Regions: A0=lo{0,1} (read ph1), A1=lo{2,3} (read ph3), B0=lb{0,1} (read
// ph1, reg-held to ph4), B1=lb{2,3} (read ph2). Quadrants (0,0),(0,1),(1,1),
// (1,0).
// STAGE RING (8 loads/thread/tile, every target >=2 barrier-pairs after its
// last reader's drain): ph1(t): A1(t+1)->nb (A1(t-1) read ph3(t-1));
// ph3(t): A0(t+2)+B0(t+2)->buf (read ph1(t), drained+barrier'd);
// ph4(t): B1(t+2)->buf (read ph2(t)).
// WAIT: vmcnt(6) at ph4 allows exactly {A0,B0,B1}(t+2) (6 loads) outstanding
// -> A1(t+1) and all earlier landed before tile t+1's reads. Never drains to
// 0 except the t=14 tail (m201's N=6 formula).
// Phase: [stage || ds_reads] ; (lgkm8 if 12 reads) ; BAR ; lgkm0 ; SCB0 ;
// setprio1 MFMA setprio0 ; BAR.   (T3+T4+T5; rule-18 fence after lgkm0)
template<int LDG>
__device__ __forceinline__ void gemm_core(const u16* gA, const u16* gB,
                                          u16* lds, int tid,
                                          f32x4 (&acc)[8][4]) {
  const int lane = tid & 63, w = tid >> 6;
  const int wr = w >> 2, wc = w & 3;
  const int l15 = lane & 15, quad = lane >> 4, xq = l15 & 7;
  const int lr = lane >> 3, lc = lane & 7;
  const int sslot = lc ^ lr;                  // pre-swizzled src 16B-slot
  const int so0 = (quad ^ xq) * 8;            // ks=0 read slot offset (elems)
  const int so1 = ((4 + quad) ^ xq) * 8;      // ks=1

  const u16* gAr = gA + (size_t)(wr * 128 + wc * 8 + lr) * LDG + sslot * 8;
  const u16* gBr = gB + (size_t)(wc * 64 + wr * 8 + lr) * LDG + sslot * 8;

  u16* dA = lds + wr * 8192 + (wc * 64 + lane) * 8;          // +buf*32768+lo*2048
  u16* dB = lds + 16384 + wc * 4096 + wr * 512 + lane * 8;   // +buf*32768+lb*1024
  const u16* pA = lds + wr * 8192 + l15 * 64;                // +buf*32768+(ih*64+i2*16)*64
  const u16* pB = lds + 16384 + wc * 4096 + l15 * 64;        // +buf*32768+(jh*2+j2)*1024

  bf16x8 af[4][2], bf0[2][2], bf1[2][2];

  auto STA = [&](int buf, int lo, int kt) {
    cp16(gAr + (size_t)lo * 32 * LDG + kt * 64, dA + buf * 32768 + lo * 2048);
  };
  auto STB = [&](int buf, int lb, int kt) {
    cp16(gBr + (size_t)lb * 16 * LDG + kt * 64, dB + buf * 32768 + lb * 1024);
  };
  auto RAF = [&](int buf, int ih) {          // 8 ds_read_b128 into af
#pragma unroll
    for (int i2 = 0; i2 < 4; ++i2) {
      const u16* p = pA + buf * 32768 + (ih * 64 + i2 * 16) * 64;
      af[i2][0] = *(const bf16x8*)(p + so0);
      af[i2][1] = *(const bf16x8*)(p + so1);
    }
  };
  auto RBF = [&](bf16x8 (&bf)[2][2], int buf, int jh) {   // 4 ds_read_b128
#pragma unroll
    for (int j2 = 0; j2 < 2; ++j2) {
      const u16* p = pB + buf * 32768 + (jh * 2 + j2) * 1024;
      bf[j2][0] = *(const bf16x8*)(p + so0);
      bf[j2][1] = *(const bf16x8*)(p + so1);
    }
  };
  auto MQ = [&](int ih, int jh, bf16x8 (&bf)[2][2]) {
    __builtin_amdgcn_s_setprio(1);
#pragma unroll
    for (int ks = 0; ks < 2; ++ks)
#pragma unroll
      for (int i2 = 0; i2 < 4; ++i2)
#pragma unroll
        for (int j2 = 0; j2 < 2; ++j2)
          acc[ih * 4 + i2][jh * 2 + j2] =
              __builtin_amdgcn_mfma_f32_16x16x32_bf16(af[i2][ks], bf[j2][ks],
                                                      acc[ih * 4 + i2][jh * 2 + j2], 0, 0, 0);
    __builtin_amdgcn_s_setprio(0);
  };

  // prologue: tile0 full (8 loads) + tile1 {A0,B0,B1} (6); vmcnt(6) -> tile0
  // landed, tile1's 6 stay in flight.
  STA(0, 0, 0); STA(0, 1, 0); STB(0, 0, 0); STB(0, 1, 0);
  STA(0, 2, 0); STA(0, 3, 0); STB(0, 2, 0); STB(0, 3, 0);
  STA(1, 0, 1); STA(1, 1, 1); STB(1, 0, 1); STB(1, 1, 1);
  STB(1, 2, 1); STB(1, 3, 1);
  WAIT6; BARX;

  auto TILE = [&](int t, int buf) {
    const int nb = buf ^ 1;
    // ---- ph1: stage A1(t+1)->nb; read af0+bf0 (12); MQ(0,0) ----
    if (t < NT - 1) { STA(nb, 2, t + 1); STA(nb, 3, t + 1); }
    RAF(buf, 0); RBF(bf0, buf, 0);
    LGKM8;
    BARX; LGKM0; SCB0;
    MQ(0, 0, bf0);
    BARX;
    // ---- ph2: read bf1 (4); MQ(0,1) ----
    RBF(bf1, buf, 1);
    BARX; LGKM0; SCB0;
    MQ(0, 1, bf1);
    BARX;
    // ---- ph3: stage A0,B0(t+2)->buf; read af1 (8); MQ(1,1) ----
    if (t < NT - 2) { STA(buf, 0, t + 2); STA(buf, 1, t + 2);
                      STB(buf, 0, t + 2); STB(buf, 1, t + 2); }
    RAF(buf, 1);
    BARX; LGKM0; SCB0;
    MQ(1, 1, bf1);
    BARX;
    // ---- ph4: stage B1(t+2)->buf; the ONE counted wait; MQ(1,0) ----
    if (t < NT - 2)       { STB(buf, 2, t + 2); STB(buf, 3, t + 2); WAIT6; }
    else if (t == NT - 2) { WAIT0; }
    BARX;
    MQ(1, 0, bf0);
    BARX;
  };

#pragma unroll 1
  for (int tt = 0; tt < 8; ++tt) {
    TILE(2 * tt,     0);
    TILE(2 * tt + 1, 1);
  }
}

// ---------------- stage 1 GEMM: C[row][m] = sigmoid(X.Wb^T + bb) - 0.5 (bf16) --
__global__ __launch_bounds__(512, 2) void gemm1_kernel(const u16* __restrict__ X,
                                                       const u16* __restrict__ W,
                                                       const float* __restrict__ bb,
                                                       u16* __restrict__ C,
                                                       float* __restrict__ kb) {
  __shared__ u16 lds[2 * 32768];
  int bid = blockIdx.x;                 // 512
  int xcd = bid & 7, idx = bid >> 3;    // XCD-affine: per-XCD 8 tm x 8 tn panel
  int tm = xcd * 8 + (idx & 7);         // 0..63
  int tn = idx >> 3;                    // 0..7
  int tid = threadIdx.x;
  f32x4 acc[8][4] = {};
  gemm_core<1024>(X + (size_t)tm * 256 * 1024, W + (size_t)tn * 256 * 1024,
                  lds, tid, acc);

  int lane = tid & 63, w = tid >> 6;
  int wr = w >> 2, wc = w & 3, l15 = lane & 15, quad = lane >> 4;
  int colb = tn * 256 + wc * 64 + l15;
  bool khalf = (tn >= 4);               // whole tile in k' half when tn>=4
  int rowb = tm * 256 + wr * 128 + quad * 4;
#pragma unroll
  for (int i = 0; i < 8; ++i) {
    float rsum[4] = {0.f, 0.f, 0.f, 0.f};
#pragma unroll
    for (int j = 0; j < 4; ++j) {
      int col = colb + j * 16;
      float bias = bb[col];
#pragma unroll
      for (int rg = 0; rg < 4; ++rg) {
        int row = rowb + i * 16 + rg;
        float v = acc[i][j][rg] + bias;
        float sg = 1.0f / (1.0f + __expf(-v));
        u16 h = f2bf(sg - 0.5f);
        C[(size_t)row * 2048 + col] = h;
        rsum[rg] += bf2f(h);   // rounded value, matches what flash's MFMA sees
      }
    }
    if (khalf) {
#pragma unroll
      for (int rg = 0; rg < 4; ++rg) {
        float s = rsum[rg];
#pragma unroll
        for (int off = 1; off < 16; off <<= 1) s += __shfl_xor(s, off);
        if (l15 == 0) atomicAdd(&kb[rowb + i * 16 + rg], 0.5f * s);
      }
    }
  }
}

// ---------------- flash: one 256q x 256k tile per block; XCD = batch ----
__global__ __launch_bounds__(512, 2) void flash_kernel(const u16* __restrict__ Cq,
                                                       const float* __restrict__ kb,
                                                       const float* __restrict__ r,
                                                       float* __restrict__ pm,
                                                       float* __restrict__ pl,
                                                       float* __restrict__ pt) {
  __shared__ u16 lds[2 * 32768];
  int bid = blockIdx.x;            // 512
  int b = bid & 7;                 // XCD-affine: each XCD owns one batch
  int idx = bid >> 3;
  int qt = idx >> 3;               // 0..7
  int kc = idx & 7;                // inner: q-tile reused from L2
  int tid = threadIdx.x;
  f32x4 acc[8][4] = {};
  gemm_core<2048>(Cq + (size_t)(b * SS + qt * 256) * 2048,
                  Cq + (size_t)(b * SS + kc * 256) * 2048 + 1024,
                  lds, tid, acc);

  int lane = tid & 63, w = tid >> 6;
  int wr = w >> 2, wc = w & 3, l15 = lane & 15, quad = lane >> 4;
  float kbv[4], rv[4];
  int colg = b * SS + kc * 256 + wc * 64 + l15;
#pragma unroll
  for (int j = 0; j < 4; ++j) { kbv[j] = kb[colg + j * 16]; rv[j] = r[colg + j * 16]; }
  int chunk = kc * 4 + wc;
  int rowb = b * SS + qt * 256 + wr * 128 + quad * 4;
#pragma unroll
  for (int i = 0; i < 8; ++i) {
#pragma unroll
    for (int rg = 0; rg < 4; ++rg) {
      float lg[4];
      float tmax = -1e30f;
#pragma unroll
      for (int j = 0; j < 4; ++j) { lg[j] = acc[i][j][rg] + kbv[j]; tmax = fmaxf(tmax, lg[j]); }
#pragma unroll
      for (int off = 1; off < 16; off <<= 1) tmax = fmaxf(tmax, __shfl_xor(tmax, off));
      float rs = 0.f, rt = 0.f;
#pragma unroll
      for (int j = 0; j < 4; ++j) {
        float p = __expf(lg[j] - tmax);
        rs += p; rt += p * rv[j];
      }
#pragma unroll
      for (int off = 1; off < 16; off <<= 1) { rs += __shfl_xor(rs, off); rt += __shfl_xor(rt, off); }
      if (l15 == 0) {
        int grow = rowb + i * 16 + rg;
        pm[(size_t)grow * NPC + chunk] = tmax;
        pl[(size_t)grow * NPC + chunk] = rs;
        pt[(size_t)grow * NPC + chunk] = rt;
      }
    }
  }
}

// ---------------- combine key-chunk partials ----------------
__global__ __launch_bounds__(256) void fixup_kernel(const float* __restrict__ pm,
                                                    const float* __restrict__ pl,
                                                    const float* __restrict__ pt,
                                                    float* __restrict__ out) {
  int row = blockIdx.x * 256 + threadIdx.x;
  float Mx = -1e30f;
#pragma unroll
  for (int c = 0; c < NPC; c++) Mx = fmaxf(Mx, pm[row * NPC + c]);
  float L = 0.f, T = 0.f;
#pragma unroll
  for (int c = 0; c < NPC; c++) {
    float a = __expf(pm[row * NPC + c] - Mx);
    L += pl[row * NPC + c] * a;
    T += pt[row * NPC + c] * a;
  }
  out[row] = T / L;
}

extern "C" void kernel_launch(void* const* d_in, const int* in_sizes, int n_in,
                              void* d_out, int out_size, void* d_ws, size_t ws_size,
                              hipStream_t stream) {
  const float* outer = (const float*)d_in[0];
  const float* mask  = (const float*)d_in[1];
  const float* Wk    = (const float*)d_in[2];
  const float* bk    = (const float*)d_in[3];
  const float* Wq    = (const float*)d_in[4];
  const float* bq    = (const float*)d_in[5];
  float* out = (float*)d_out;

  char* ws = (char*)d_ws;
  size_t off = 0;
  auto alloc = [&](size_t bytes) -> void* {
    void* p = ws + off;
    off = (off + bytes + 255) & ~(size_t)255;
    return p;
  };
  u16* Xb  = (u16*)alloc((size_t)MT * NN * 2);       // 32 MB bf16 outer
  u16* Wb  = (u16*)alloc((size_t)2048 * NN * 2);     // 4 MB bf16 [Wq;Wk]
  u16* Cq  = (u16*)alloc((size_t)MT * 2048 * 2);     // 64 MB bf16 [q'|k']
  float* bb = (float*)alloc(2048 * 4);
  float* rr = (float*)alloc((size_t)MT * 4);
  float* kb = (float*)alloc((size_t)MT * 4);
  float* pm = (float*)alloc((size_t)MT * NPC * 4);
  float* pl = (float*)alloc((size_t)MT * NPC * 4);
  float* pt = (float*)alloc((size_t)MT * NPC * 4);

  prep_x_kernel<<<dim3(MT / 4), dim3(256), 0, stream>>>(outer, mask, Xb, rr, kb);
  prep_w_kernel<<<dim3(2048), dim3(256), 0, stream>>>(Wq, Wk, bq, bk, Wb, bb);
  gemm1_kernel<<<dim3(512), dim3(512), 0, stream>>>(Xb, Wb, bb, Cq, kb);
  flash_kernel<<<dim3(512), dim3(512), 0, stream>>>(Cq, kb, rr, pm, pl, pt);
  fixup_kernel<<<dim3(MT / 256), dim3(256), 0, stream>>>(pm, pl, pt, out);
}

// Round 7
// 261.183 us; speedup vs baseline: 1.0549x; 1.0549x over previous
//
#include <hip/hip_runtime.h>
#include <hip/hip_bf16.h>

#define BB 8
#define SS 2048
#define NN 1024
#define MT (BB*SS)   // 16384
#define NPC 32       // partial chunks per row (8 kc-tiles * 4 wave-columns)
#define NT 16        // K tiles of 64

typedef __attribute__((ext_vector_type(8))) short bf16x8;
typedef __attribute__((ext_vector_type(4))) float f32x4;
typedef unsigned short u16;
typedef unsigned int u32;

__device__ __forceinline__ u16 f2bf(float f) {
  u32 u = __float_as_uint(f);
  u += 0x7fff + ((u >> 16) & 1);
  return (u16)(u >> 16);
}
__device__ __forceinline__ float bf2f(u16 h) {
  return __uint_as_float(((u32)h) << 16);
}

typedef __attribute__((address_space(1))) void GV;
typedef __attribute__((address_space(3))) void LV;
__device__ __forceinline__ void cp16(const void* g, void* l) {
  __builtin_amdgcn_global_load_lds((GV*)g, (LV*)l, 16, 0, 0);
}

#define WAIT8 asm volatile("s_waitcnt vmcnt(8)" ::: "memory")
#define WAIT0 asm volatile("s_waitcnt vmcnt(0)" ::: "memory")
#define LGKM4 asm volatile("s_waitcnt lgkmcnt(4)" ::: "memory")
#define LGKM0 asm volatile("s_waitcnt lgkmcnt(0)" ::: "memory")
#define BARX  __builtin_amdgcn_s_barrier()
#define SCB0  __builtin_amdgcn_sched_barrier(0)

// ------- fused prep: blocks <4096 cast outer (+rowsum, kb=mask); rest cast W --
__global__ __launch_bounds__(256) void prep_kernel(const float* __restrict__ outer,
                                                   const float* __restrict__ mask,
                                                   const float* __restrict__ Wq,
                                                   const float* __restrict__ Wk,
                                                   const float* __restrict__ bq,
                                                   const float* __restrict__ bk,
                                                   u16* __restrict__ Xb,
                                                   float* __restrict__ r,
                                                   float* __restrict__ kb,
                                                   u16* __restrict__ Wb,
                                                   float* __restrict__ bb) {
  int bid = blockIdx.x;
  if (bid < 4096) {
    int w = threadIdx.x >> 6, lane = threadIdx.x & 63;
    int row = bid * 4 + w;
    const float4* src = (const float4*)(outer + (size_t)row * NN);
    ushort4* dst = (ushort4*)(Xb + (size_t)row * NN);
    float s = 0.f;
#pragma unroll
    for (int u = 0; u < 4; u++) {
      int idx = lane + u * 64;
      float4 v = src[idx];
      ushort4 o;
      o.x = f2bf(v.x); o.y = f2bf(v.y); o.z = f2bf(v.z); o.w = f2bf(v.w);
      dst[idx] = o;
      s += (v.x + v.y) + (v.z + v.w);
    }
#pragma unroll
    for (int off = 1; off < 64; off <<= 1) s += __shfl_xor(s, off);
    if (lane == 0) { r[row] = s; kb[row] = mask[row]; }
  } else {
    int idx = (bid - 4096) * 256 + threadIdx.x;   // 0 .. 524287 (x4 elems)
    int e = idx * 4;
    int rowm = e >> 10;
    int col = e & 1023;
    const float* srcp = (rowm < NN) ? (Wq + (size_t)rowm * NN + col)
                                    : (Wk + (size_t)(rowm - NN) * NN + col);
    float4 v = *(const float4*)srcp;
    ushort4 o; o.x = f2bf(v.x); o.y = f2bf(v.y); o.z = f2bf(v.z); o.w = f2bf(v.w);
    *(ushort4*)(Wb + (size_t)e) = o;
    if (idx < 2 * NN) bb[idx] = (idx < NN) ? bq[idx] : bk[idx - NN];
  }
}

// ==== 256x256 / BK=64 / TWO-phase, TWO-barrier per K-tile / counted vmcnt ====
// LDS per buf (64KB): A half0(16KB) A half1(16KB) Bq0..Bq3(8KB each). 2 bufs.
// Occupancy is register-bound to 1 block/CU (252 regs/thread) -> every barrier
// is a full-CU convoy; this version halves barriers/tile vs R5 (4 -> 2).
// P1(t): stage A1(t+1)->nb; vmcnt(8) [retires tile t's 8 loads, keeps t+1's 8
//   in flight]; BAR; issue all 16 ds_reads (af0,bf0,bf1); lgkm(4)->af0+bf0;
//   MQ(0,0); lgkm(0)->bf1; MQ(0,1); trailing-issue af1 (af regs dead).
// P2(t): BAR; stage A0,B0,B1(t+2)->buf; lgkm(0)->af1; MQ(1,1); MQ(1,0) [bf0
//   register-held across P1->P2, as in R5].
// Hazards (write-after-read, per region): every P2 stage targets regions whose
// tile-t reads were ISSUED by all waves before the P2 barrier (program order:
// reads precede it); writes land >=~500cy after issue, reads retire in-order
// well before. A1(t+1) staged at P1-top: its prior reads (af1(t-1)) were
// issued before P2(t-1)'s barrier, one rendezvous + vmem latency of margin.
// Numerics: identical MFMA sequence/order to R5 (bit-identical results).
template<int LDG>
__device__ __forceinline__ void gemm_core(const u16* gA, const u16* gB,
                                          u16* lds, int tid,
                                          f32x4 (&acc)[8][4]) {
  const int lane = tid & 63, w = tid >> 6;
  const int wr = w >> 2, wc = w & 3;
  const int l15 = lane & 15, quad = lane >> 4, xq = l15 & 7;
  const int lr = lane >> 3, lc = lane & 7;
  const int sslot = lc ^ lr;                  // pre-swizzled src 16B-slot
  const int so0 = (quad ^ xq) * 8;            // ks=0 read slot offset (elems)
  const int so1 = ((4 + quad) ^ xq) * 8;      // ks=1

  const u16* gAr = gA + (size_t)(wr * 128 + wc * 8 + lr) * LDG + sslot * 8;
  const u16* gBr = gB + (size_t)(wc * 64 + wr * 8 + lr) * LDG + sslot * 8;

  u16* dA = lds + wr * 8192 + (wc * 64 + lane) * 8;          // +buf*32768+lo*2048
  u16* dB = lds + 16384 + wc * 4096 + wr * 512 + lane * 8;   // +buf*32768+lb*1024
  const u16* pA = lds + wr * 8192 + l15 * 64;                // +buf*32768+(ih*64+i2*16)*64
  const u16* pB = lds + 16384 + wc * 4096 + l15 * 64;        // +buf*32768+(jh*2+j2)*1024

  bf16x8 af[4][2], bf0[2][2], bf1[2][2];

  auto STA = [&](int buf, int lo, int kt) {
    cp16(gAr + (size_t)lo * 32 * LDG + kt * 64, dA + buf * 32768 + lo * 2048);
  };
  auto STB = [&](int buf, int lb, int kt) {
    cp16(gBr + (size_t)lb * 16 * LDG + kt * 64, dB + buf * 32768 + lb * 1024);
  };
  auto RAF = [&](int buf, int ih) {          // 8 ds_read_b128 into af
#pragma unroll
    for (int i2 = 0; i2 < 4; ++i2) {
      const u16* p = pA + buf * 32768 + (ih * 64 + i2 * 16) * 64;
      af[i2][0] = *(const bf16x8*)(p + so0);
      af[i2][1] = *(const bf16x8*)(p + so1);
    }
  };
  auto RBF = [&](bf16x8 (&bf)[2][2], int buf, int jh) {   // 4 ds_read_b128
#pragma unroll
    for (int j2 = 0; j2 < 2; ++j2) {
      const u16* p = pB + buf * 32768 + (jh * 2 + j2) * 1024;
      bf[j2][0] = *(const bf16x8*)(p + so0);
      bf[j2][1] = *(const bf16x8*)(p + so1);
    }
  };
  auto MQ = [&](int ih, int jh, bf16x8 (&bf)[2][2]) {
    __builtin_amdgcn_s_setprio(1);
#pragma unroll
    for (int ks = 0; ks < 2; ++ks)
#pragma unroll
      for (int i2 = 0; i2 < 4; ++i2)
#pragma unroll
        for (int j2 = 0; j2 < 2; ++j2)
          acc[ih * 4 + i2][jh * 2 + j2] =
              __builtin_amdgcn_mfma_f32_16x16x32_bf16(af[i2][ks], bf[j2][ks],
                                                      acc[ih * 4 + i2][jh * 2 + j2], 0, 0, 0);
    __builtin_amdgcn_s_setprio(0);
  };

  // prologue: tile0 full (8 loads) + tile1 {A0,B0,B1} (6). No wait/barrier
  // here: TILE(0)'s P1 does [stage A1(1); vmcnt(8); BAR] which lands tile 0
  // and leaves tile 1's 8 in flight.
  STA(0, 0, 0); STA(0, 1, 0); STB(0, 0, 0); STB(0, 1, 0);
  STA(0, 2, 0); STA(0, 3, 0); STB(0, 2, 0); STB(0, 3, 0);
  STA(1, 0, 1); STA(1, 1, 1); STB(1, 0, 1); STB(1, 1, 1);
  STB(1, 2, 1); STB(1, 3, 1);

  auto TILE = [&](int t, int buf) {
    const int nb = buf ^ 1;
    // ---- P1 ----
    if (t < NT - 1) { STA(nb, 2, t + 1); STA(nb, 3, t + 1); WAIT8; }
    else            { WAIT0; }
    BARX;
    RAF(buf, 0); RBF(bf0, buf, 0); RBF(bf1, buf, 1);
    LGKM4; SCB0;
    MQ(0, 0, bf0);
    LGKM0; SCB0;
    MQ(0, 1, bf1);
    SCB0;
    RAF(buf, 1);
    // ---- P2 ----
    BARX;
    if (t < NT - 2) { STA(buf, 0, t + 2); STA(buf, 1, t + 2);
                      STB(buf, 0, t + 2); STB(buf, 1, t + 2);
                      STB(buf, 2, t + 2); STB(buf, 3, t + 2); }
    LGKM0; SCB0;
    MQ(1, 1, bf1);
    MQ(1, 0, bf0);
  };

#pragma unroll 1
  for (int tt = 0; tt < 8; ++tt) {
    TILE(2 * tt,     0);
    TILE(2 * tt + 1, 1);
  }
}

// ---------------- stage 1 GEMM: C[row][m] = sigmoid(X.Wb^T + bb) - 0.5 (bf16) --
__global__ __launch_bounds__(512, 2) void gemm1_kernel(const u16* __restrict__ X,
                                                       const u16* __restrict__ W,
                                                       const float* __restrict__ bb,
                                                       u16* __restrict__ C,
                                                       float* __restrict__ kb) {
  __shared__ u16 lds[2 * 32768];
  int bid = blockIdx.x;                 // 512
  int xcd = bid & 7, idx = bid >> 3;    // XCD-affine: per-XCD 8 tm x 8 tn panel
  int tm = xcd * 8 + (idx & 7);         // 0..63
  int tn = idx >> 3;                    // 0..7
  int tid = threadIdx.x;
  f32x4 acc[8][4] = {};
  gemm_core<1024>(X + (size_t)tm * 256 * 1024, W + (size_t)tn * 256 * 1024,
                  lds, tid, acc);

  int lane = tid & 63, w = tid >> 6;
  int wr = w >> 2, wc = w & 3, l15 = lane & 15, quad = lane >> 4;
  int colb = tn * 256 + wc * 64 + l15;
  bool khalf = (tn >= 4);               // whole tile in k' half when tn>=4
  int rowb = tm * 256 + wr * 128 + quad * 4;
#pragma unroll
  for (int i = 0; i < 8; ++i) {
    float rsum[4] = {0.f, 0.f, 0.f, 0.f};
#pragma unroll
    for (int j = 0; j < 4; ++j) {
      int col = colb + j * 16;
      float bias = bb[col];
#pragma unroll
      for (int rg = 0; rg < 4; ++rg) {
        int row = rowb + i * 16 + rg;
        float v = acc[i][j][rg] + bias;
        float sg = 1.0f / (1.0f + __expf(-v));
        u16 h = f2bf(sg - 0.5f);
        C[(size_t)row * 2048 + col] = h;
        rsum[rg] += bf2f(h);   // rounded value, matches what flash's MFMA sees
      }
    }
    if (khalf) {
#pragma unroll
      for (int rg = 0; rg < 4; ++rg) {
        float s = rsum[rg];
#pragma unroll
        for (int off = 1; off < 16; off <<= 1) s += __shfl_xor(s, off);
        if (l15 == 0) atomicAdd(&kb[rowb + i * 16 + rg], 0.5f * s);
      }
    }
  }
}

// ---------------- flash: one 256q x 256k tile per block; XCD = batch ----
__global__ __launch_bounds__(512, 2) void flash_kernel(const u16* __restrict__ Cq,
                                                       const float* __restrict__ kb,
                                                       const float* __restrict__ r,
                                                       float* __restrict__ pm,
                                                       float* __restrict__ pl,
                                                       float* __restrict__ pt) {
  __shared__ u16 lds[2 * 32768];
  int bid = blockIdx.x;            // 512
  int b = bid & 7;                 // XCD-affine: each XCD owns one batch
  int idx = bid >> 3;
  int qt = idx >> 3;               // 0..7
  int kc = idx & 7;                // inner: q-tile reused from L2
  int tid = threadIdx.x;
  f32x4 acc[8][4] = {};
  gemm_core<2048>(Cq + (size_t)(b * SS + qt * 256) * 2048,
                  Cq + (size_t)(b * SS + kc * 256) * 2048 + 1024,
                  lds, tid, acc);

  int lane = tid & 63, w = tid >> 6;
  int wr = w >> 2, wc = w & 3, l15 = lane & 15, quad = lane >> 4;
  float kbv[4], rv[4];
  int colg = b * SS + kc * 256 + wc * 64 + l15;
#pragma unroll
  for (int j = 0; j < 4; ++j) { kbv[j] = kb[colg + j * 16]; rv[j] = r[colg + j * 16]; }
  int chunk = kc * 4 + wc;
  int rowb = b * SS + qt * 256 + wr * 128 + quad * 4;
#pragma unroll
  for (int i = 0; i < 8; ++i) {
#pragma unroll
    for (int rg = 0; rg < 4; ++rg) {
      float lg[4];
      float tmax = -1e30f;
#pragma unroll
      for (int j = 0; j < 4; ++j) { lg[j] = acc[i][j][rg] + kbv[j]; tmax = fmaxf(tmax, lg[j]); }
#pragma unroll
      for (int off = 1; off < 16; off <<= 1) tmax = fmaxf(tmax, __shfl_xor(tmax, off));
      float rs = 0.f, rt = 0.f;
#pragma unroll
      for (int j = 0; j < 4; ++j) {
        float p = __expf(lg[j] - tmax);
        rs += p; rt += p * rv[j];
      }
#pragma unroll
      for (int off = 1; off < 16; off <<= 1) { rs += __shfl_xor(rs, off); rt += __shfl_xor(rt, off); }
      if (l15 == 0) {
        int grow = rowb + i * 16 + rg;
        pm[(size_t)grow * NPC + chunk] = tmax;
        pl[(size_t)grow * NPC + chunk] = rs;
        pt[(size_t)grow * NPC + chunk] = rt;
      }
    }
  }
}

// ---------------- combine key-chunk partials ----------------
__global__ __launch_bounds__(256) void fixup_kernel(const float* __restrict__ pm,
                                                    const float* __restrict__ pl,
                                                    const float* __restrict__ pt,
                                                    float* __restrict__ out) {
  int row = blockIdx.x * 256 + threadIdx.x;
  float Mx = -1e30f;
#pragma unroll
  for (int c = 0; c < NPC; c++) Mx = fmaxf(Mx, pm[row * NPC + c]);
  float L = 0.f, T = 0.f;
#pragma unroll
  for (int c = 0; c < NPC; c++) {
    float a = __expf(pm[row * NPC + c] - Mx);
    L += pl[row * NPC + c] * a;
    T += pt[row * NPC + c] * a;
  }
  out[row] = T / L;
}

extern "C" void kernel_launch(void* const* d_in, const int* in_sizes, int n_in,
                              void* d_out, int out_size, void* d_ws, size_t ws_size,
                              hipStream_t stream) {
  const float* outer = (const float*)d_in[0];
  const float* mask  = (const float*)d_in[1];
  const float* Wk    = (const float*)d_in[2];
  const float* bk    = (const float*)d_in[3];
  const float* Wq    = (const float*)d_in[4];
  const float* bq    = (const float*)d_in[5];
  float* out = (float*)d_out;

  char* ws = (char*)d_ws;
  size_t off = 0;
  auto alloc = [&](size_t bytes) -> void* {
    void* p = ws + off;
    off = (off + bytes + 255) & ~(size_t)255;
    return p;
  };
  u16* Xb  = (u16*)alloc((size_t)MT * NN * 2);       // 32 MB bf16 outer
  u16* Wb  = (u16*)alloc((size_t)2048 * NN * 2);     // 4 MB bf16 [Wq;Wk]
  u16* Cq  = (u16*)alloc((size_t)MT * 2048 * 2);     // 64 MB bf16 [q'|k']
  float* bb = (float*)alloc(2048 * 4);
  float* rr = (float*)alloc((size_t)MT * 4);
  float* kb = (float*)alloc((size_t)MT * 4);
  float* pm = (float*)alloc((size_t)MT * NPC * 4);
  float* pl = (float*)alloc((size_t)MT * NPC * 4);
  float* pt = (float*)alloc((size_t)MT * NPC * 4);

  prep_kernel<<<dim3(6144), dim3(256), 0, stream>>>(outer, mask, Wq, Wk, bq, bk,
                                                    Xb, rr, kb, Wb, bb);
  gemm1_kernel<<<dim3(512), dim3(512), 0, stream>>>(Xb, Wb, bb, Cq, kb);
  flash_kernel<<<dim3(512), dim3(512), 0, stream>>>(Cq, kb, rr, pm, pl, pt);
  fixup_kernel<<<dim3(MT / 256), dim3(256), 0, stream>>>(pm, pl, pt, out);
}